// Round 1
// baseline (534.193 us; speedup 1.0000x reference)
//
#include <hip/hip_runtime.h>
#include <hip/hip_bf16.h>
#include <hip/hip_fp16.h>

// Problem constants (B=2, T=2048, DIM=1024, FF=4096, E=8, TOPK=2)
#define NTOK 4096
#define DIM 1024
#define FF 4096
#define NE 8
#define NSLOT 8192   // NTOK * TOPK

typedef _Float16 half8 __attribute__((ext_vector_type(8)));
typedef float floatx4 __attribute__((ext_vector_type(4)));

__device__ __forceinline__ float gelu_exact(float x) {
    return 0.5f * x * (1.0f + erff(x * 0.70710678118654752f));
}

// ---------------- convert x (fp32 -> fp16) ----------------
__global__ __launch_bounds__(256) void k_convert_x(const float* __restrict__ x,
                                                   _Float16* __restrict__ xh) {
    int i = (blockIdx.x * 256 + threadIdx.x) * 8;   // total NTOK*DIM = 4,194,304
    float4 a = *(const float4*)(x + i);
    float4 b = *(const float4*)(x + i + 4);
    half8 h;
    h[0] = (_Float16)a.x; h[1] = (_Float16)a.y; h[2] = (_Float16)a.z; h[3] = (_Float16)a.w;
    h[4] = (_Float16)b.x; h[5] = (_Float16)b.y; h[6] = (_Float16)b.z; h[7] = (_Float16)b.w;
    *(half8*)(xh + i) = h;
}

// ---------------- router: fp32 logits, top-2, softmax ----------------
__global__ __launch_bounds__(256) void k_router(const float* __restrict__ x,
                                                const float* __restrict__ Wr,
                                                int* __restrict__ counts,
                                                int* __restrict__ tok_e,
                                                float* __restrict__ tok_w,
                                                int* __restrict__ tok_pos) {
    __shared__ float wr[NE * DIM];   // 32 KB
    int tid = threadIdx.x;
    for (int i = tid; i < NE * DIM / 4; i += 256)
        ((float4*)wr)[i] = ((const float4*)Wr)[i];
    __syncthreads();

    int w = tid >> 6, lane = tid & 63;
    int t = blockIdx.x * 4 + w;

    float acc[NE] = {};
    for (int j = 0; j < DIM / 64; ++j) {
        float xv = x[t * DIM + j * 64 + lane];
#pragma unroll
        for (int e = 0; e < NE; ++e)
            acc[e] += xv * wr[e * DIM + j * 64 + lane];
    }
#pragma unroll
    for (int e = 0; e < NE; ++e) {
#pragma unroll
        for (int s = 32; s; s >>= 1) acc[e] += __shfl_xor(acc[e], s, 64);
    }
    if (lane == 0) {
        int b0 = 0; float m0 = acc[0];
#pragma unroll
        for (int e = 1; e < NE; ++e) { if (acc[e] > m0) { m0 = acc[e]; b0 = e; } }
        int b1 = -1; float m1 = -1e30f;
#pragma unroll
        for (int e = 0; e < NE; ++e) { if (e != b0 && acc[e] > m1) { m1 = acc[e]; b1 = e; } }
        float z = __expf(m1 - m0);               // m1 <= m0, z in (0,1]
        float zz = 1.0f / (1.0f + z);
        float w0 = zz;
        float w1 = z * zz;
        int p0 = atomicAdd(&counts[b0], 1);
        int p1 = atomicAdd(&counts[b1], 1);
        tok_e[2 * t] = b0;  tok_e[2 * t + 1] = b1;
        tok_w[2 * t] = w0;  tok_w[2 * t + 1] = w1;
        tok_pos[2 * t] = p0; tok_pos[2 * t + 1] = p1;
    }
}

// ---------------- tiny prefix sum over 8 counts ----------------
__global__ void k_prefix(const int* __restrict__ counts, int* __restrict__ offs) {
    if (threadIdx.x == 0 && blockIdx.x == 0) {
        int s = 0;
        for (int e = 0; e < NE; ++e) { offs[e] = s; s += counts[e]; }
        offs[NE] = s;
    }
}

// ---------------- slot assignment ----------------
__global__ __launch_bounds__(256) void k_slots(const int* __restrict__ offs,
                                               const int* __restrict__ tok_e,
                                               const int* __restrict__ tok_pos,
                                               int* __restrict__ tok_slot,
                                               int* __restrict__ list_tok) {
    int idx = blockIdx.x * 256 + threadIdx.x;   // 0..8191
    if (idx < NSLOT) {
        int e = tok_e[idx];
        int slot = offs[e] + tok_pos[idx];
        tok_slot[idx] = slot;
        list_tok[slot] = idx >> 1;
    }
}

// ---------------- FFN1: h = gelu(x @ W1[e]), gathered rows ----------------
// tile 128 rows x 128 ff, BK=64, 256 threads (4 waves 2x2 of 64x64)
__global__ __launch_bounds__(256) void k_ffn1(const _Float16* __restrict__ xh,
                                              const float* __restrict__ W1,
                                              const int* __restrict__ counts,
                                              const int* __restrict__ offs,
                                              const int* __restrict__ list_tok,
                                              _Float16* __restrict__ hbuf) {
    int e = blockIdx.z;
    int cnt = counts[e];
    int mt = blockIdx.y;
    if (mt * 128 >= cnt) return;
    int f0 = blockIdx.x * 128;
    int base = offs[e] + mt * 128;

    __shared__ _Float16 lds[16384];       // 32 KB
    _Float16* As = lds;                   // [128 rows][8 chunks of 8 halfs], XOR swizzled
    _Float16* Bs = lds + 8192;            // [128 f]  [8 chunks], XOR swizzled

    int tid = threadIdx.x;
    // A staging: thread -> (row = tid>>1, chunks (tid&1)*4 .. +3)
    int arow = tid >> 1;
    int ac0 = (tid & 1) * 4;
    int tok = list_tok[(mt * 128 + arow < cnt) ? (base + arow) : base];
    const _Float16* aptr = xh + (size_t)tok * DIM;
    // B staging: thread -> (f = tid&127, k-range (tid>>7)*32 .. +31)
    int bf = tid & 127;
    int bkg = (tid >> 7) * 32;
    const float* bptr = W1 + (size_t)e * DIM * FF + (f0 + bf);

    floatx4 acc[4][4];
#pragma unroll
    for (int m = 0; m < 4; ++m)
#pragma unroll
        for (int n = 0; n < 4; ++n) acc[m][n] = (floatx4){0.f, 0.f, 0.f, 0.f};

    int wid = tid >> 6, lane = tid & 63;
    int wm = (wid >> 1) * 64, wn = (wid & 1) * 64;
    int la = lane & 15, lb = lane >> 4;

    for (int k0 = 0; k0 < DIM; k0 += 64) {
        // stage A (gathered fp16 rows): 4 x 16B per thread
#pragma unroll
        for (int j = 0; j < 4; ++j) {
            int c = ac0 + j;
            half8 v = *(const half8*)(aptr + k0 + c * 8);
            *(half8*)(As + arow * 64 + ((c ^ (arow & 7)) * 8)) = v;
        }
        // stage B (transpose + fp32->fp16): 32 strided dword loads per thread
#pragma unroll
        for (int j = 0; j < 4; ++j) {
            half8 v;
#pragma unroll
            for (int i = 0; i < 8; ++i)
                v[i] = (_Float16)bptr[(size_t)(k0 + bkg + j * 8 + i) * FF];
            int c = (bkg >> 3) + j;
            *(half8*)(Bs + bf * 64 + ((c ^ (bf & 7)) * 8)) = v;
        }
        __syncthreads();
#pragma unroll
        for (int kk = 0; kk < 2; ++kk) {
            half8 af[4], bfr[4];
#pragma unroll
            for (int m = 0; m < 4; ++m) {
                int row = wm + m * 16 + la;
                int c = kk * 4 + lb;
                af[m] = *(const half8*)(As + row * 64 + ((c ^ (row & 7)) * 8));
            }
#pragma unroll
            for (int n = 0; n < 4; ++n) {
                int row = wn + n * 16 + la;
                int c = kk * 4 + lb;
                bfr[n] = *(const half8*)(Bs + row * 64 + ((c ^ (row & 7)) * 8));
            }
#pragma unroll
            for (int m = 0; m < 4; ++m)
#pragma unroll
                for (int n = 0; n < 4; ++n)
                    acc[m][n] = __builtin_amdgcn_mfma_f32_16x16x32_f16(af[m], bfr[n], acc[m][n], 0, 0, 0);
        }
        __syncthreads();
    }

    // epilogue: gelu, fp16, LDS transpose per wave, coalesced 16B stores
    _Float16* tw = lds + wid * 4096;      // 64x64 halfs per wave
#pragma unroll
    for (int m = 0; m < 4; ++m)
#pragma unroll
        for (int n = 0; n < 4; ++n) {
            floatx4 v = acc[m][n];
#pragma unroll
            for (int i = 0; i < 4; ++i) {
                int row = m * 16 + lb * 4 + i;
                int col = n * 16 + la;
                tw[row * 64 + col] = (_Float16)gelu_exact(v[i]);
            }
        }
    __syncthreads();
    int valid = cnt - mt * 128;           // rows valid in this tile
#pragma unroll
    for (int i = 0; i < 8; ++i) {
        int gi = i * 64 + lane;           // chunk id within wave tile
        int row = gi >> 3, c8 = gi & 7;
        half8 v = *(const half8*)(tw + gi * 8);
        int trow = wm + row;
        if (trow < valid)
            *(half8*)(hbuf + (size_t)(base + trow) * FF + f0 + wn + c8 * 8) = v;
    }
}

// ---------------- FFN2: y = h @ W2[e] (fp32 out rows) ----------------
__global__ __launch_bounds__(256) void k_ffn2(const _Float16* __restrict__ hbuf,
                                              const float* __restrict__ W2,
                                              const int* __restrict__ counts,
                                              const int* __restrict__ offs,
                                              float* __restrict__ ybuf) {
    int e = blockIdx.z;
    int cnt = counts[e];
    int mt = blockIdx.y;
    if (mt * 128 >= cnt) return;
    int f0 = blockIdx.x * 128;            // 8 tiles over DIM
    int base = offs[e] + mt * 128;

    __shared__ _Float16 lds[16384];
    _Float16* As = lds;
    _Float16* Bs = lds + 8192;

    int tid = threadIdx.x;
    int arow = tid >> 1;
    int ac0 = (tid & 1) * 4;
    int rg = base + arow; if (rg > NSLOT - 1) rg = NSLOT - 1;
    const _Float16* aptr = hbuf + (size_t)rg * FF;
    int bf = tid & 127;
    int bkg = (tid >> 7) * 32;
    const float* bptr = W2 + (size_t)e * FF * DIM + (f0 + bf);

    floatx4 acc[4][4];
#pragma unroll
    for (int m = 0; m < 4; ++m)
#pragma unroll
        for (int n = 0; n < 4; ++n) acc[m][n] = (floatx4){0.f, 0.f, 0.f, 0.f};

    int wid = tid >> 6, lane = tid & 63;
    int wm = (wid >> 1) * 64, wn = (wid & 1) * 64;
    int la = lane & 15, lb = lane >> 4;

    for (int k0 = 0; k0 < FF; k0 += 64) {
#pragma unroll
        for (int j = 0; j < 4; ++j) {
            int c = ac0 + j;
            half8 v = *(const half8*)(aptr + k0 + c * 8);
            *(half8*)(As + arow * 64 + ((c ^ (arow & 7)) * 8)) = v;
        }
#pragma unroll
        for (int j = 0; j < 4; ++j) {
            half8 v;
#pragma unroll
            for (int i = 0; i < 8; ++i)
                v[i] = (_Float16)bptr[(size_t)(k0 + bkg + j * 8 + i) * DIM];
            int c = (bkg >> 3) + j;
            *(half8*)(Bs + bf * 64 + ((c ^ (bf & 7)) * 8)) = v;
        }
        __syncthreads();
#pragma unroll
        for (int kk = 0; kk < 2; ++kk) {
            half8 af[4], bfr[4];
#pragma unroll
            for (int m = 0; m < 4; ++m) {
                int row = wm + m * 16 + la;
                int c = kk * 4 + lb;
                af[m] = *(const half8*)(As + row * 64 + ((c ^ (row & 7)) * 8));
            }
#pragma unroll
            for (int n = 0; n < 4; ++n) {
                int row = wn + n * 16 + la;
                int c = kk * 4 + lb;
                bfr[n] = *(const half8*)(Bs + row * 64 + ((c ^ (row & 7)) * 8));
            }
#pragma unroll
            for (int m = 0; m < 4; ++m)
#pragma unroll
                for (int n = 0; n < 4; ++n)
                    acc[m][n] = __builtin_amdgcn_mfma_f32_16x16x32_f16(af[m], bfr[n], acc[m][n], 0, 0, 0);
        }
        __syncthreads();
    }

    int valid = cnt - mt * 128;
#pragma unroll
    for (int m = 0; m < 4; ++m)
#pragma unroll
        for (int n = 0; n < 4; ++n) {
            floatx4 v = acc[m][n];
#pragma unroll
            for (int i = 0; i < 4; ++i) {
                int row = wm + m * 16 + lb * 4 + i;
                if (row < valid)
                    ybuf[(size_t)(base + row) * DIM + f0 + wn + n * 16 + la] = v[i];
            }
        }
}

// ---------------- combine: out[t] = w0*y[slot0] + w1*y[slot1] ----------------
__global__ __launch_bounds__(256) void k_combine(const float* __restrict__ ybuf,
                                                 const int* __restrict__ tok_slot,
                                                 const float* __restrict__ tok_w,
                                                 float* __restrict__ out) {
    int t = blockIdx.x;
    int d = threadIdx.x * 4;
    int s0 = tok_slot[2 * t], s1 = tok_slot[2 * t + 1];
    float w0 = tok_w[2 * t], w1 = tok_w[2 * t + 1];
    float4 y0 = *(const float4*)(ybuf + (size_t)s0 * DIM + d);
    float4 y1 = *(const float4*)(ybuf + (size_t)s1 * DIM + d);
    float4 o;
    o.x = w0 * y0.x + w1 * y1.x;
    o.y = w0 * y0.y + w1 * y1.y;
    o.z = w0 * y0.z + w1 * y1.z;
    o.w = w0 * y0.w + w1 * y1.w;
    *(float4*)(out + (size_t)t * DIM + d) = o;
}

extern "C" void kernel_launch(void* const* d_in, const int* in_sizes, int n_in,
                              void* d_out, int out_size, void* d_ws, size_t ws_size,
                              hipStream_t stream) {
    const float* x  = (const float*)d_in[0];   // [4096,1024]
    const float* Wr = (const float*)d_in[1];   // [8,1024]
    const float* W1 = (const float*)d_in[2];   // [8,1024,4096]
    const float* W2 = (const float*)d_in[3];   // [8,4096,1024]
    float* out = (float*)d_out;

    // workspace layout (~104.2 MiB total)
    char* ws = (char*)d_ws;
    _Float16* xh   = (_Float16*)ws;                                   //  8,388,608
    _Float16* hbuf = (_Float16*)(ws + 8388608);                       // 67,108,864
    float*    ybuf = (float*)(ws + 8388608 + 67108864);               // 33,554,432
    char* p = ws + 8388608 + 67108864 + 33554432;
    int*   counts   = (int*)p;        p += 256;
    int*   offs     = (int*)p;        p += 256;
    int*   tok_e    = (int*)p;        p += NSLOT * 4;
    float* tok_w    = (float*)p;      p += NSLOT * 4;
    int*   tok_pos  = (int*)p;        p += NSLOT * 4;
    int*   tok_slot = (int*)p;        p += NSLOT * 4;
    int*   list_tok = (int*)p;        p += NSLOT * 4;

    hipMemsetAsync(counts, 0, NE * sizeof(int), stream);
    k_convert_x<<<NTOK * DIM / (256 * 8), 256, 0, stream>>>(x, xh);
    k_router<<<NTOK / 4, 256, 0, stream>>>(x, Wr, counts, tok_e, tok_w, tok_pos);
    k_prefix<<<1, 64, 0, stream>>>(counts, offs);
    k_slots<<<NSLOT / 256, 256, 0, stream>>>(offs, tok_e, tok_pos, tok_slot, list_tok);
    k_ffn1<<<dim3(FF / 128, NTOK / 128, NE), 256, 0, stream>>>(xh, W1, counts, offs, list_tok, hbuf);
    k_ffn2<<<dim3(DIM / 128, NTOK / 128, NE), 256, 0, stream>>>(hbuf, W2, counts, offs, ybuf);
    k_combine<<<NTOK, 256, 0, stream>>>(ybuf, tok_slot, tok_w, out);
}

// Round 2
// 500.248 us; speedup vs baseline: 1.0679x; 1.0679x over previous
//
#include <hip/hip_runtime.h>
#include <hip/hip_bf16.h>
#include <hip/hip_fp16.h>

// Problem constants (B=2, T=2048, DIM=1024, FF=4096, E=8, TOPK=2)
#define NTOK 4096
#define DIM 1024
#define FF 4096
#define NE 8
#define NSLOT 8192   // NTOK * TOPK

typedef _Float16 half8 __attribute__((ext_vector_type(8)));
typedef _Float16 half4 __attribute__((ext_vector_type(4)));
typedef float floatx4 __attribute__((ext_vector_type(4)));

__device__ __forceinline__ float gelu_exact(float x) {
    return 0.5f * x * (1.0f + erff(x * 0.70710678118654752f));
}

// async global->LDS, 16B per lane; LDS dest is wave-uniform base + lane*16
__device__ __forceinline__ void gl_lds16(const void* g, void* l) {
    __builtin_amdgcn_global_load_lds(
        (const __attribute__((address_space(1))) void*)g,
        (__attribute__((address_space(3))) void*)l, 16, 0, 0);
}

// ---------------- convert x (fp32 -> fp16) ----------------
__global__ __launch_bounds__(256) void k_convert_x(const float* __restrict__ x,
                                                   _Float16* __restrict__ xh) {
    int i = (blockIdx.x * 256 + threadIdx.x) * 8;
    float4 a = *(const float4*)(x + i);
    float4 b = *(const float4*)(x + i + 4);
    half8 h;
    h[0] = (_Float16)a.x; h[1] = (_Float16)a.y; h[2] = (_Float16)a.z; h[3] = (_Float16)a.w;
    h[4] = (_Float16)b.x; h[5] = (_Float16)b.y; h[6] = (_Float16)b.z; h[7] = (_Float16)b.w;
    *(half8*)(xh + i) = h;
}

// ---------------- transpose+convert: src fp32 [E][R][C] -> dst fp16 [E][C][R] ----------------
// grid: (C/64, R/64, E), block 256
__global__ __launch_bounds__(256) void k_transpose(const float* __restrict__ src,
                                                   _Float16* __restrict__ dst,
                                                   int R, int C) {
    __shared__ float t[64][65];
    int e = blockIdx.z;
    const float* s = src + (size_t)e * R * C;
    _Float16* d = dst + (size_t)e * C * R;
    int r0 = blockIdx.y * 64, c0 = blockIdx.x * 64;
    int tid = threadIdx.x;
    int rr = tid >> 4, cc = (tid & 15) * 4;
#pragma unroll
    for (int i = 0; i < 4; ++i) {
        float4 v = *(const float4*)(s + (size_t)(r0 + rr + i * 16) * C + c0 + cc);
        t[rr + i * 16][cc] = v.x; t[rr + i * 16][cc + 1] = v.y;
        t[rr + i * 16][cc + 2] = v.z; t[rr + i * 16][cc + 3] = v.w;
    }
    __syncthreads();
    int f = tid >> 3, ch = tid & 7;
#pragma unroll
    for (int j = 0; j < 2; ++j) {
        int fr = f + j * 32;
        half8 v;
#pragma unroll
        for (int u = 0; u < 8; ++u) v[u] = (_Float16)t[ch * 8 + u][fr];
        *(half8*)(d + (size_t)(c0 + fr) * R + r0 + ch * 8) = v;
    }
}

// ---------------- router: fp32 logits, top-2, softmax ----------------
__global__ __launch_bounds__(256) void k_router(const float* __restrict__ x,
                                                const float* __restrict__ Wr,
                                                int* __restrict__ counts,
                                                int* __restrict__ tok_e,
                                                float* __restrict__ tok_w,
                                                int* __restrict__ tok_pos) {
    __shared__ float wr[NE * DIM];   // 32 KB
    int tid = threadIdx.x;
    for (int i = tid; i < NE * DIM / 4; i += 256)
        ((float4*)wr)[i] = ((const float4*)Wr)[i];
    __syncthreads();

    int w = tid >> 6, lane = tid & 63;
    int t = blockIdx.x * 4 + w;

    float acc[NE] = {};
    for (int j = 0; j < DIM / 64; ++j) {
        float xv = x[t * DIM + j * 64 + lane];
#pragma unroll
        for (int e = 0; e < NE; ++e)
            acc[e] += xv * wr[e * DIM + j * 64 + lane];
    }
#pragma unroll
    for (int e = 0; e < NE; ++e) {
#pragma unroll
        for (int s = 32; s; s >>= 1) acc[e] += __shfl_xor(acc[e], s, 64);
    }
    if (lane == 0) {
        int b0 = 0; float m0 = acc[0];
#pragma unroll
        for (int e = 1; e < NE; ++e) { if (acc[e] > m0) { m0 = acc[e]; b0 = e; } }
        int b1 = -1; float m1 = -1e30f;
#pragma unroll
        for (int e = 0; e < NE; ++e) { if (e != b0 && acc[e] > m1) { m1 = acc[e]; b1 = e; } }
        float z = __expf(m1 - m0);
        float zz = 1.0f / (1.0f + z);
        int p0 = atomicAdd(&counts[b0], 1);
        int p1 = atomicAdd(&counts[b1], 1);
        tok_e[2 * t] = b0;  tok_e[2 * t + 1] = b1;
        tok_w[2 * t] = zz;  tok_w[2 * t + 1] = z * zz;
        tok_pos[2 * t] = p0; tok_pos[2 * t + 1] = p1;
    }
}

// ---------------- tiny prefix sum over 8 counts ----------------
__global__ void k_prefix(const int* __restrict__ counts, int* __restrict__ offs) {
    if (threadIdx.x == 0 && blockIdx.x == 0) {
        int s = 0;
        for (int e = 0; e < NE; ++e) { offs[e] = s; s += counts[e]; }
        offs[NE] = s;
    }
}

// ---------------- slot assignment ----------------
__global__ __launch_bounds__(256) void k_slots(const int* __restrict__ offs,
                                               const int* __restrict__ tok_e,
                                               const int* __restrict__ tok_pos,
                                               int* __restrict__ tok_slot,
                                               int* __restrict__ list_tok) {
    int idx = blockIdx.x * 256 + threadIdx.x;
    if (idx < NSLOT) {
        int e = tok_e[idx];
        int slot = offs[e] + tok_pos[idx];
        tok_slot[idx] = slot;
        list_tok[slot] = idx >> 1;
    }
}

// ---------------- FFN1: h = gelu(x @ W1[e]) using w1t fp16 [E][FF][DIM] ----------------
// tile 128 rows x 128 ff, BK=64, 256 threads (4 waves 2x2 of 64x64)
__global__ __launch_bounds__(256) void k_ffn1(const _Float16* __restrict__ xh,
                                              const _Float16* __restrict__ w1t,
                                              const int* __restrict__ counts,
                                              const int* __restrict__ offs,
                                              const int* __restrict__ list_tok,
                                              _Float16* __restrict__ hbuf) {
    int e = blockIdx.z;
    int cnt = counts[e];
    int mt = blockIdx.y;
    if (mt * 128 >= cnt) return;
    int f0 = blockIdx.x * 128;
    int base = offs[e] + mt * 128;
    int valid = cnt - mt * 128;

    __shared__ _Float16 lds[16384];       // 32 KB: As 16KB + Bs 16KB
    _Float16* As = lds;
    _Float16* Bs = lds + 8192;

    int tid = threadIdx.x;
    int wid = tid >> 6, lane = tid & 63;

    // staging: wave w stages LDS chunks [w*256, w*256+256) of each tile,
    // 4 global_load_lds x 16B per wave per tile per k-step.
    // linear chunk g holds logical chunk c = (g&7)^(r&7) of row r=g>>3 (XOR swizzle)
    const char* xb = (const char*)xh;
    const char* wb = (const char*)(w1t + (size_t)e * FF * DIM);
    size_t aoff[4], boff[4];
#pragma unroll
    for (int i = 0; i < 4; ++i) {
        int g = wid * 256 + i * 64 + lane;
        int r = g >> 3;
        int c = (g & 7) ^ (r & 7);
        int rr = (r < valid) ? r : 0;
        int tok = list_tok[base + rr];
        aoff[i] = (size_t)tok * (DIM * 2) + c * 16;
        boff[i] = (size_t)(f0 + r) * (DIM * 2) + c * 16;
    }

    floatx4 acc[4][4];
#pragma unroll
    for (int m = 0; m < 4; ++m)
#pragma unroll
        for (int n = 0; n < 4; ++n) acc[m][n] = (floatx4){0.f, 0.f, 0.f, 0.f};

    int wm = (wid >> 1) * 64, wn = (wid & 1) * 64;
    int la = lane & 15, lb = lane >> 4;

    for (int k0 = 0; k0 < DIM; k0 += 64) {
#pragma unroll
        for (int i = 0; i < 4; ++i)
            gl_lds16(xb + aoff[i] + k0 * 2, As + wid * 2048 + i * 512);
#pragma unroll
        for (int i = 0; i < 4; ++i)
            gl_lds16(wb + boff[i] + k0 * 2, Bs + wid * 2048 + i * 512);
        __syncthreads();
#pragma unroll
        for (int kk = 0; kk < 2; ++kk) {
            half8 af[4], bfr[4];
#pragma unroll
            for (int m = 0; m < 4; ++m) {
                int row = wm + m * 16 + la;
                int c = kk * 4 + lb;
                af[m] = *(const half8*)(As + row * 64 + ((c ^ (row & 7)) * 8));
            }
#pragma unroll
            for (int n = 0; n < 4; ++n) {
                int row = wn + n * 16 + la;
                int c = kk * 4 + lb;
                bfr[n] = *(const half8*)(Bs + row * 64 + ((c ^ (row & 7)) * 8));
            }
#pragma unroll
            for (int m = 0; m < 4; ++m)
#pragma unroll
                for (int n = 0; n < 4; ++n)
                    acc[m][n] = __builtin_amdgcn_mfma_f32_16x16x32_f16(af[m], bfr[n], acc[m][n], 0, 0, 0);
        }
        __syncthreads();
    }

    // epilogue: gelu, fp16, per-wave LDS transpose, coalesced 16B stores
    _Float16* tw = lds + wid * 4096;      // 64x64 halfs per wave
#pragma unroll
    for (int m = 0; m < 4; ++m)
#pragma unroll
        for (int n = 0; n < 4; ++n) {
            floatx4 v = acc[m][n];
#pragma unroll
            for (int i = 0; i < 4; ++i) {
                int row = m * 16 + lb * 4 + i;
                int col = n * 16 + la;
                tw[row * 64 + col] = (_Float16)gelu_exact(v[i]);
            }
        }
    __syncthreads();
#pragma unroll
    for (int i = 0; i < 8; ++i) {
        int gi = i * 64 + lane;
        int row = gi >> 3, c8 = gi & 7;
        half8 v = *(const half8*)(tw + gi * 8);
        int trow = wm + row;
        if (trow < valid)
            *(half8*)(hbuf + (size_t)(base + trow) * FF + f0 + wn + c8 * 8) = v;
    }
}

// ---------------- FFN2: y = h @ W2[e] using w2t fp16 [E][DIM][FF], fp16 out ----------------
__global__ __launch_bounds__(256) void k_ffn2(const _Float16* __restrict__ hbuf,
                                              const _Float16* __restrict__ w2t,
                                              const int* __restrict__ counts,
                                              const int* __restrict__ offs,
                                              _Float16* __restrict__ yh) {
    int e = blockIdx.z;
    int cnt = counts[e];
    int mt = blockIdx.y;
    if (mt * 128 >= cnt) return;
    int f0 = blockIdx.x * 128;            // over DIM
    int base = offs[e] + mt * 128;
    int valid = cnt - mt * 128;

    __shared__ _Float16 lds[16384];
    _Float16* As = lds;
    _Float16* Bs = lds + 8192;

    int tid = threadIdx.x;
    int wid = tid >> 6, lane = tid & 63;

    const char* hb = (const char*)hbuf;
    const char* wb = (const char*)(w2t + (size_t)e * DIM * FF);
    size_t aoff[4], boff[4];
#pragma unroll
    for (int i = 0; i < 4; ++i) {
        int g = wid * 256 + i * 64 + lane;
        int r = g >> 3;
        int c = (g & 7) ^ (r & 7);
        int rr = (r < valid) ? r : 0;
        aoff[i] = (size_t)(base + rr) * (FF * 2) + c * 16;
        boff[i] = (size_t)(f0 + r) * (FF * 2) + c * 16;
    }

    floatx4 acc[4][4];
#pragma unroll
    for (int m = 0; m < 4; ++m)
#pragma unroll
        for (int n = 0; n < 4; ++n) acc[m][n] = (floatx4){0.f, 0.f, 0.f, 0.f};

    int wm = (wid >> 1) * 64, wn = (wid & 1) * 64;
    int la = lane & 15, lb = lane >> 4;

    for (int k0 = 0; k0 < FF; k0 += 64) {
#pragma unroll
        for (int i = 0; i < 4; ++i)
            gl_lds16(hb + aoff[i] + k0 * 2, As + wid * 2048 + i * 512);
#pragma unroll
        for (int i = 0; i < 4; ++i)
            gl_lds16(wb + boff[i] + k0 * 2, Bs + wid * 2048 + i * 512);
        __syncthreads();
#pragma unroll
        for (int kk = 0; kk < 2; ++kk) {
            half8 af[4], bfr[4];
#pragma unroll
            for (int m = 0; m < 4; ++m) {
                int row = wm + m * 16 + la;
                int c = kk * 4 + lb;
                af[m] = *(const half8*)(As + row * 64 + ((c ^ (row & 7)) * 8));
            }
#pragma unroll
            for (int n = 0; n < 4; ++n) {
                int row = wn + n * 16 + la;
                int c = kk * 4 + lb;
                bfr[n] = *(const half8*)(Bs + row * 64 + ((c ^ (row & 7)) * 8));
            }
#pragma unroll
            for (int m = 0; m < 4; ++m)
#pragma unroll
                for (int n = 0; n < 4; ++n)
                    acc[m][n] = __builtin_amdgcn_mfma_f32_16x16x32_f16(af[m], bfr[n], acc[m][n], 0, 0, 0);
        }
        __syncthreads();
    }

    // epilogue: fp16, per-wave LDS transpose, coalesced 16B stores
    _Float16* tw = lds + wid * 4096;
#pragma unroll
    for (int m = 0; m < 4; ++m)
#pragma unroll
        for (int n = 0; n < 4; ++n) {
            floatx4 v = acc[m][n];
#pragma unroll
            for (int i = 0; i < 4; ++i) {
                int row = m * 16 + lb * 4 + i;
                int col = n * 16 + la;
                tw[row * 64 + col] = (_Float16)v[i];
            }
        }
    __syncthreads();
#pragma unroll
    for (int i = 0; i < 8; ++i) {
        int gi = i * 64 + lane;
        int row = gi >> 3, c8 = gi & 7;
        half8 v = *(const half8*)(tw + gi * 8);
        int trow = wm + row;
        if (trow < valid)
            *(half8*)(yh + (size_t)(base + trow) * DIM + f0 + wn + c8 * 8) = v;
    }
}

// ---------------- combine: out[t] = w0*y[slot0] + w1*y[slot1] ----------------
__global__ __launch_bounds__(256) void k_combine(const _Float16* __restrict__ yh,
                                                 const int* __restrict__ tok_slot,
                                                 const float* __restrict__ tok_w,
                                                 float* __restrict__ out) {
    int t = blockIdx.x;
    int d = threadIdx.x * 4;
    int s0 = tok_slot[2 * t], s1 = tok_slot[2 * t + 1];
    float w0 = tok_w[2 * t], w1 = tok_w[2 * t + 1];
    half4 y0 = *(const half4*)(yh + (size_t)s0 * DIM + d);
    half4 y1 = *(const half4*)(yh + (size_t)s1 * DIM + d);
    float4 o;
    o.x = w0 * (float)y0[0] + w1 * (float)y1[0];
    o.y = w0 * (float)y0[1] + w1 * (float)y1[1];
    o.z = w0 * (float)y0[2] + w1 * (float)y1[2];
    o.w = w0 * (float)y0[3] + w1 * (float)y1[3];
    *(float4*)(out + (size_t)t * DIM + d) = o;
}

extern "C" void kernel_launch(void* const* d_in, const int* in_sizes, int n_in,
                              void* d_out, int out_size, void* d_ws, size_t ws_size,
                              hipStream_t stream) {
    const float* x  = (const float*)d_in[0];   // [4096,1024]
    const float* Wr = (const float*)d_in[1];   // [8,1024]
    const float* W1 = (const float*)d_in[2];   // [8,1024,4096]
    const float* W2 = (const float*)d_in[3];   // [8,4096,1024]
    float* out = (float*)d_out;

    // workspace layout (~159.6 MiB), w2t aliases w1t (w1t dead after FFN1)
    char* ws = (char*)d_ws;
    _Float16* w1t  = (_Float16*)ws;                        // 67,108,864 B
    _Float16* w2t  = (_Float16*)ws;                        // aliases w1t
    _Float16* xh   = (_Float16*)(ws + 67108864);           //  8,388,608 B
    _Float16* hbuf = (_Float16*)(ws + 75497472);           // 67,108,864 B
    _Float16* yh   = (_Float16*)(ws + 142606336);          // 16,777,216 B
    char* p = ws + 159383552;
    int*   counts   = (int*)p;        p += 256;
    int*   offs     = (int*)p;        p += 256;
    int*   tok_e    = (int*)p;        p += NSLOT * 4;
    float* tok_w    = (float*)p;      p += NSLOT * 4;
    int*   tok_pos  = (int*)p;        p += NSLOT * 4;
    int*   tok_slot = (int*)p;        p += NSLOT * 4;
    int*   list_tok = (int*)p;        p += NSLOT * 4;

    hipMemsetAsync(counts, 0, NE * sizeof(int), stream);
    k_convert_x<<<NTOK * DIM / (256 * 8), 256, 0, stream>>>(x, xh);
    k_router<<<NTOK / 4, 256, 0, stream>>>(x, Wr, counts, tok_e, tok_w, tok_pos);
    k_prefix<<<1, 64, 0, stream>>>(counts, offs);
    k_slots<<<NSLOT / 256, 256, 0, stream>>>(offs, tok_e, tok_pos, tok_slot, list_tok);
    // W1 [E][D][FF] -> w1t [E][FF][D]
    k_transpose<<<dim3(FF / 64, DIM / 64, NE), 256, 0, stream>>>(W1, w1t, DIM, FF);
    k_ffn1<<<dim3(FF / 128, NSLOT / 128, NE), 256, 0, stream>>>(xh, w1t, counts, offs, list_tok, hbuf);
    // W2 [E][FF][D] -> w2t [E][D][FF]  (w1t no longer needed)
    k_transpose<<<dim3(DIM / 64, FF / 64, NE), 256, 0, stream>>>(W2, w2t, FF, DIM);
    k_ffn2<<<dim3(DIM / 128, NSLOT / 128, NE), 256, 0, stream>>>(hbuf, w2t, counts, offs, yh);
    k_combine<<<NTOK, 256, 0, stream>>>(yh, tok_slot, tok_w, out);
}